// Round 1
// baseline (596.122 us; speedup 1.0000x reference)
//
#include <hip/hip_runtime.h>
#include <math.h>

#define KS  15
#define RAD 7
#define L   160
#define VOL (L*L*L)
#define WT  32
#define HT  16

struct Taps {
    float g[KS];   // normalized 1D gaussian
    float h[KS];   // (x^2 - s^2)/s^4 * g
    float m;       // kernel mean (subtracted constant)
    float scale;   // 1 / (N * VOL)
};

// ---------------- Pass 1: along W (contiguous). diff -> A,B,C ----------------
__global__ __launch_bounds__(320) void k_wpass(const float* __restrict__ pred,
                                               const float* __restrict__ tgt,
                                               float* __restrict__ A,
                                               float* __restrict__ B,
                                               float* __restrict__ C,
                                               Taps tp) {
    __shared__ float s[2][L + 2 * RAD];
    const int w  = threadIdx.x;          // 0..159
    const int ty = threadIdx.y;          // 0..1
    const int h  = blockIdx.x * 2 + ty;
    const int d  = blockIdx.y;
    const int base = (d * L + h) * L;

    s[ty][RAD + w] = pred[base + w] - tgt[base + w];
    if (w < RAD) { s[ty][w] = 0.f; s[ty][L + RAD + w] = 0.f; }
    __syncthreads();

    float a = 0.f, b = 0.f, c = 0.f;
#pragma unroll
    for (int t = 0; t < KS; ++t) {
        float v = s[ty][w + t];
        a += tp.g[t] * v;
        b += tp.h[t] * v;
        c += v;
    }
    A[base + w] = a;
    B[base + w] = b;
    C[base + w] = c;
}

// ---------------- Pass 2: along H. A,B,C -> P,Q,R ----------------
__global__ __launch_bounds__(512) void k_hpass(const float* __restrict__ A,
                                               const float* __restrict__ B,
                                               const float* __restrict__ C,
                                               float* __restrict__ P,
                                               float* __restrict__ Q,
                                               float* __restrict__ R,
                                               Taps tp) {
    __shared__ float sA[HT + 2 * RAD][WT];
    __shared__ float sB[HT + 2 * RAD][WT];
    __shared__ float sC[HT + 2 * RAD][WT];
    const int tx = threadIdx.x, ty = threadIdx.y;
    const int w  = blockIdx.x * WT + tx;
    const int h0 = blockIdx.y * HT;
    const int d  = blockIdx.z;

    for (int r = ty; r < HT + 2 * RAD; r += HT) {
        int hs = h0 - RAD + r;
        bool ok = (hs >= 0) && (hs < L);
        int idx = (d * L + hs) * L + w;
        sA[r][tx] = ok ? A[idx] : 0.f;
        sB[r][tx] = ok ? B[idx] : 0.f;
        sC[r][tx] = ok ? C[idx] : 0.f;
    }
    __syncthreads();

    float p = 0.f, q = 0.f, rr = 0.f;
#pragma unroll
    for (int t = 0; t < KS; ++t) {
        float va = sA[ty + t][tx];
        float vb = sB[ty + t][tx];
        p  += tp.g[t] * va;
        q  += tp.h[t] * va + tp.g[t] * vb;
        rr += sC[ty + t][tx];
    }
    const int idx = (d * L + (h0 + ty)) * L + w;
    P[idx] = p;
    Q[idx] = q;
    R[idx] = rr;
}

// ---------------- Pass 3: along D + |.| + reduction ----------------
__global__ __launch_bounds__(512) void k_dpass(const float* __restrict__ P,
                                               const float* __restrict__ Q,
                                               const float* __restrict__ R,
                                               float* __restrict__ out,
                                               Taps tp) {
    __shared__ float sP[HT + 2 * RAD][WT];
    __shared__ float sQ[HT + 2 * RAD][WT];
    __shared__ float sR[HT + 2 * RAD][WT];
    const int tx = threadIdx.x, ty = threadIdx.y;
    const int w  = blockIdx.x * WT + tx;
    const int d0 = blockIdx.y * HT;
    const int h  = blockIdx.z;

    for (int r = ty; r < HT + 2 * RAD; r += HT) {
        int ds = d0 - RAD + r;
        bool ok = (ds >= 0) && (ds < L);
        int idx = (ds * L + h) * L + w;
        sP[r][tx] = ok ? P[idx] : 0.f;
        sQ[r][tx] = ok ? Q[idx] : 0.f;
        sR[r][tx] = ok ? R[idx] : 0.f;
    }
    __syncthreads();

    float f = 0.f, box = 0.f;
#pragma unroll
    for (int t = 0; t < KS; ++t) {
        f   += tp.h[t] * sP[ty + t][tx] + tp.g[t] * sQ[ty + t][tx];
        box += sR[ty + t][tx];
    }
    f -= tp.m * box;
    float val = fabsf(f) * tp.scale;

    // 64-lane wave reduce, then cross-wave via LDS, one atomic per block
#pragma unroll
    for (int off = 32; off > 0; off >>= 1) val += __shfl_down(val, off);

    __shared__ float wsum[8];
    const int tid  = ty * WT + tx;
    const int lane = tid & 63;
    const int wid  = tid >> 6;
    if (lane == 0) wsum[wid] = val;
    __syncthreads();
    if (wid == 0) {
        float v = (lane < 8) ? wsum[lane] : 0.f;
#pragma unroll
        for (int off = 4; off > 0; off >>= 1) v += __shfl_down(v, off);
        if (lane == 0) atomicAdd(out, v);
    }
}

extern "C" void kernel_launch(void* const* d_in, const int* in_sizes, int n_in,
                              void* d_out, int out_size, void* d_ws, size_t ws_size,
                              hipStream_t stream) {
    const float* pred = (const float*)d_in[0];
    const float* tgt  = (const float*)d_in[1];
    float* out = (float*)d_out;
    float* ws  = (float*)d_ws;

    // Build 1D taps on host (double precision, cast to float)
    Taps tp;
    const double sigma = 1.5;
    double g1[KS], S = 0.0;
    for (int i = 0; i < KS; ++i) {
        double x = (double)(i - RAD);
        g1[i] = exp(-x * x / (2.0 * sigma * sigma));
        S += g1[i];
    }
    double sumH = 0.0;
    for (int i = 0; i < KS; ++i) {
        double x = (double)(i - RAD);
        double G = g1[i] / S;
        double H = (x * x - sigma * sigma) / (sigma * sigma * sigma * sigma) * G;
        tp.g[i] = (float)G;
        tp.h[i] = (float)H;
        sumH += H;
    }
    tp.m     = (float)(3.0 * sumH / (double)(KS * KS * KS));
    tp.scale = 1.0f / (4.0f * (float)VOL);

    float* A = ws + (size_t)0 * VOL;
    float* B = ws + (size_t)1 * VOL;
    float* C = ws + (size_t)2 * VOL;
    float* P = ws + (size_t)3 * VOL;
    float* Q = ws + (size_t)4 * VOL;
    float* R = ws + (size_t)5 * VOL;

    hipMemsetAsync(d_out, 0, sizeof(float), stream);

    for (int n = 0; n < 4; ++n) {
        const float* pn = pred + (size_t)n * VOL;
        const float* tn = tgt  + (size_t)n * VOL;
        k_wpass<<<dim3(L / 2, L), dim3(L, 2), 0, stream>>>(pn, tn, A, B, C, tp);
        k_hpass<<<dim3(L / WT, L / HT, L), dim3(WT, HT), 0, stream>>>(A, B, C, P, Q, R, tp);
        k_dpass<<<dim3(L / WT, L / HT, L), dim3(WT, HT), 0, stream>>>(P, Q, R, out, tp);
    }
}